// Round 1
// baseline (6874.840 us; speedup 1.0000x reference)
//
#include <hip/hip_runtime.h>
#include <math.h>

// RnnModelInterp: 199-step stacked tanh RNN with softmax/linear heads and
// NaN imputation feedback. Round 1: correctness-first multi-kernel pipeline.
// Per step: [A] h0 = tanh([val|h0|cat] @ Wcat0 + b0)
//           [B] h1 = tanh([h0|h1] @ Wcat1 + b1)
//           [C] heads + softmax + output + impute next inputs.
// Kernel boundaries provide the inter-phase ordering; state double-buffered in ws.

#define SZ_WCAT0 (579u * 512u)            // 296448
#define OFF_WCAT0 0u
#define OFF_WCAT1 (OFF_WCAT0 + SZ_WCAT0)  // 296448
#define SZ_WCAT1 (1024u * 512u)           // 524288
#define OFF_H0 (OFF_WCAT1 + SZ_WCAT1)     // 820736 (phase-B pad reads spill here: zeroed/bounded, never NaN)
#define SZ_HBUF (256u * 512u)             // 131072
#define OFF_H1 (OFF_H0 + 2u * SZ_HBUF)    // 1082880
#define OFF_CAT (OFF_H1 + 2u * SZ_HBUF)   // 1345024
#define SZ_CATB (256u * 3u)               // 768
#define OFF_VAL (OFF_CAT + 2u * SZ_CATB)  // 1346560
#define SZ_VALB (256u * 64u)              // 16384
// total ws need: 1379328 floats = ~5.3 MB

__device__ __forceinline__ bool nanf_bits(float v) {
  return (__float_as_uint(v) & 0x7fffffffu) > 0x7f800000u;
}

// Pack weights into concatenated row-major [K][512] buffers.
// Wcat0 rows: [0,64)=W_ih0 rows 3..66 (val), [64,576)=W_hh0, [576,579)=W_ih0 rows 0..2 (cat)
// Wcat1 rows: [0,512)=W_ih1, [512,1024)=W_hh1
__global__ __launch_bounds__(256) void pack_weights(
    const float* __restrict__ Wih0, const float* __restrict__ Whh0,
    const float* __restrict__ Wih1, const float* __restrict__ Whh1,
    float* __restrict__ Wc0, float* __restrict__ Wc1) {
  unsigned idx = blockIdx.x * 256u + threadIdx.x;
  unsigned stride = gridDim.x * 256u;
  for (unsigned i = idx; i < SZ_WCAT0; i += stride) {
    unsigned r = i >> 9, c = i & 511u;
    float v;
    if (r < 64u)       v = Wih0[(3u + r) * 512u + c];
    else if (r < 576u) v = Whh0[(r - 64u) * 512u + c];
    else               v = Wih0[(r - 576u) * 512u + c];
    Wc0[i] = v;
  }
  for (unsigned i = idx; i < SZ_WCAT1; i += stride) {
    unsigned r = i >> 9, c = i & 511u;
    Wc1[i] = (r < 512u) ? Wih1[r * 512u + c] : Whh1[(r - 512u) * 512u + c];
  }
}

__global__ __launch_bounds__(256) void init_state(
    const float* __restrict__ cat_seq, const float* __restrict__ val_seq,
    float* __restrict__ h0a, float* __restrict__ h1a,
    float* __restrict__ cata, float* __restrict__ vala) {
  unsigned idx = blockIdx.x * 256u + threadIdx.x;  // grid 512 -> 131072 threads
  h0a[idx] = 0.f;
  h1a[idx] = 0.f;
  if (idx < SZ_CATB) cata[idx] = cat_seq[idx];
  if (idx < SZ_VALB) vala[idx] = val_seq[idx];
}

// Fused GEMM + bias + tanh. Tile: 8 rows x 64 cols per block, grid (32,8).
// 256 threads: 64 items (2 rows x 4 cols) x 4-way K-split, LDS reduce at end.
// PHASE 0: K=579 (pad 592), A = [val(64) | h0(512) | cat(3)]
// PHASE 1: K=1024 (pad 1040), A = [h0_new(512) | h1_prev(512)]
// Zero-padded LDS columns make all K-ranges multiples of 4; weight reads past
// K land in valid (non-NaN) ws memory and are multiplied by zero.
template <int PHASE>
__global__ __launch_bounds__(256) void step_gemm(
    const float* __restrict__ a0, const float* __restrict__ a1,
    const float* __restrict__ a2, const float* __restrict__ W,
    const float* __restrict__ bias, float* __restrict__ out) {
  constexpr int KS = (PHASE == 0) ? 592 : 1040;
  __shared__ float As[8 * KS];
  __shared__ float red[2048];
  const int tid = threadIdx.x;
  const int row0 = blockIdx.x * 8;

  if (PHASE == 0) {
    if (tid < 128) {  // val: 8 rows x 16 quads
      int r = tid >> 4, q = tid & 15;
      *(float4*)&As[r * KS + q * 4] = *(const float4*)&a0[(row0 + r) * 64 + q * 4];
    }
    for (int i = tid; i < 1024; i += 256) {  // h0: 8 rows x 128 quads
      int r = i >> 7, q = i & 127;
      *(float4*)&As[r * KS + 64 + q * 4] = *(const float4*)&a1[(row0 + r) * 512 + q * 4];
    }
    if (tid < 24) {  // cat: 8 rows x 3
      int r = tid / 3, j = tid % 3;
      As[r * KS + 576 + j] = a2[(row0 + r) * 3 + j];
    }
    if (tid < 104) {  // zero pad cols [579,592)
      int r = tid / 13, j = tid % 13;
      As[r * KS + 579 + j] = 0.f;
    }
  } else {
    for (int i = tid; i < 1024; i += 256) {
      int r = i >> 7, q = i & 127;
      *(float4*)&As[r * KS + q * 4] = *(const float4*)&a0[(row0 + r) * 512 + q * 4];
    }
    for (int i = tid; i < 1024; i += 256) {
      int r = i >> 7, q = i & 127;
      *(float4*)&As[r * KS + 512 + q * 4] = *(const float4*)&a1[(row0 + r) * 512 + q * 4];
    }
    if (tid < 128) {  // zero pad cols [1024,1040)
      int r = tid >> 4, j = tid & 15;
      As[r * KS + 1024 + j] = 0.f;
    }
  }
  __syncthreads();

  const int kg = tid >> 6, item = tid & 63;
  const int rp = (tid >> 4) & 3, qx = tid & 15;
  const int r0 = 2 * rp, r1 = r0 + 1;
  const int colb = blockIdx.y * 64 + qx * 4;
  const int kq = KS / 4;  // 148 or 260, both %4==0
  const int ka = kg * kq;
  float acc0[4] = {0, 0, 0, 0}, acc1[4] = {0, 0, 0, 0};
  const float* Wp = W + (size_t)ka * 512 + colb;
  const float* A0p = &As[r0 * KS + ka];
  const float* A1p = &As[r1 * KS + ka];
  for (int k = 0; k < kq; k += 4) {
    float4 A0 = *(const float4*)(A0p + k);
    float4 A1 = *(const float4*)(A1p + k);
    float a0c[4] = {A0.x, A0.y, A0.z, A0.w};
    float a1c[4] = {A1.x, A1.y, A1.z, A1.w};
#pragma unroll
    for (int j = 0; j < 4; ++j) {
      float4 wj = *(const float4*)(Wp + j * 512);
      acc0[0] += a0c[j] * wj.x; acc0[1] += a0c[j] * wj.y;
      acc0[2] += a0c[j] * wj.z; acc0[3] += a0c[j] * wj.w;
      acc1[0] += a1c[j] * wj.x; acc1[1] += a1c[j] * wj.y;
      acc1[2] += a1c[j] * wj.z; acc1[3] += a1c[j] * wj.w;
    }
    Wp += 2048;
  }
#pragma unroll
  for (int a = 0; a < 4; ++a) {
    red[kg * 512 + item * 8 + a] = acc0[a];
    red[kg * 512 + item * 8 + 4 + a] = acc1[a];
  }
  __syncthreads();
  if (tid < 64) {
    float s[8];
#pragma unroll
    for (int a = 0; a < 8; ++a)
      s[a] = red[item * 8 + a] + red[512 + item * 8 + a] +
             red[1024 + item * 8 + a] + red[1536 + item * 8 + a];
    float4 o0, o1;
    o0.x = tanhf(s[0] + bias[colb + 0]);
    o0.y = tanhf(s[1] + bias[colb + 1]);
    o0.z = tanhf(s[2] + bias[colb + 2]);
    o0.w = tanhf(s[3] + bias[colb + 3]);
    o1.x = tanhf(s[4] + bias[colb + 0]);
    o1.y = tanhf(s[5] + bias[colb + 1]);
    o1.z = tanhf(s[6] + bias[colb + 2]);
    o1.w = tanhf(s[7] + bias[colb + 3]);
    *(float4*)&out[(row0 + r0) * 512 + colb] = o0;
    *(float4*)&out[(row0 + r1) * 512 + colb] = o1;
  }
}

// Heads + softmax + output + imputation. Grid 32 blocks (8 rows each).
__global__ __launch_bounds__(256) void phase_c(
    const float* __restrict__ h1n, const float* __restrict__ valp,
    const float* __restrict__ cat_seq, const float* __restrict__ val_seq,
    const float* __restrict__ Wc, const float* __restrict__ bc,
    const float* __restrict__ Wm, const float* __restrict__ bm,
    float* __restrict__ out, float* __restrict__ catn,
    float* __restrict__ valn, int step) {
  __shared__ float h1s[8 * 512];
  __shared__ float redc[4 * 64 * 8];
  __shared__ float redc2[192];
  __shared__ float catd[24];
  const int tid = threadIdx.x;
  const int row0 = blockIdx.x * 8;
  for (int i = tid; i < 1024; i += 256) {
    int r = i >> 7, q = i & 127;
    *(float4*)&h1s[r * 512 + q * 4] = *(const float4*)&h1n[(row0 + r) * 512 + q * 4];
  }
  __syncthreads();

  // o_val = h1 @ Wm + bm + val_cur ; 64 cols x 4-way K-split
  const int m = tid & 63, sub = tid >> 6;
  float acc[8] = {0, 0, 0, 0, 0, 0, 0, 0};
  {
    const float* wmp = Wm + (size_t)(sub * 128) * 64 + m;
    const int kb = sub * 128;
    for (int k = 0; k < 128; ++k) {
      float w = wmp[(size_t)k * 64];
#pragma unroll
      for (int r = 0; r < 8; ++r) acc[r] += h1s[r * 512 + kb + k] * w;
    }
  }
#pragma unroll
  for (int r = 0; r < 8; ++r) redc[sub * 512 + m * 8 + r] = acc[r];
  __syncthreads();

  if (tid < 64) {  // finalize o_val + impute val_next (col m = tid)
#pragma unroll
    for (int r = 0; r < 8; ++r) {
      float s = redc[tid * 8 + r] + redc[512 + tid * 8 + r] +
                redc[1024 + tid * 8 + r] + redc[1536 + tid * 8 + r];
      float ov = s + bm[tid] + valp[(row0 + r) * 64 + tid];
      float raw = val_seq[(size_t)(step + 1) * (256 * 64) + (row0 + r) * 64 + tid];
      valn[(row0 + r) * 64 + tid] = nanf_bits(raw) ? ov : raw;
    }
  } else {  // cat head partials: 24 dots x 8 K-splits over 192 threads
    int l = tid - 64;
    int d = l % 24, ks = l / 24;
    int r = d / 3, j = d % 3;
    float a = 0.f;
    const int kb = ks * 64;
    for (int k = 0; k < 64; ++k) a += h1s[r * 512 + kb + k] * Wc[(kb + k) * 3 + j];
    redc2[ks * 24 + d] = a;
  }
  __syncthreads();
  if (tid < 24) {
    float s = bc[tid % 3];
#pragma unroll
    for (int ks = 0; ks < 8; ++ks) s += redc2[ks * 24 + tid];
    catd[tid] = s;
  }
  __syncthreads();
  if (tid < 8) {
    int r = tid;
    float a0 = catd[r * 3 + 0], a1 = catd[r * 3 + 1], a2 = catd[r * 3 + 2];
    float mx = fmaxf(a0, fmaxf(a1, a2));
    float e0 = expf(a0 - mx), e1 = expf(a1 - mx), e2 = expf(a2 - mx);
    float inv = 1.f / (e0 + e1 + e2);
    float p0 = e0 * inv, p1 = e1 * inv, p2 = e2 * inv;
    size_t ob = (size_t)step * (256 * 3) + (size_t)(row0 + r) * 3;
    out[ob + 0] = p0; out[ob + 1] = p1; out[ob + 2] = p2;
    size_t cb = (size_t)(step + 1) * (256 * 3) + (size_t)(row0 + r) * 3;
    float c0 = cat_seq[cb + 0], c1 = cat_seq[cb + 1], c2 = cat_seq[cb + 2];
    catn[(row0 + r) * 3 + 0] = nanf_bits(c0) ? p0 : c0;
    catn[(row0 + r) * 3 + 1] = nanf_bits(c1) ? p1 : c1;
    catn[(row0 + r) * 3 + 2] = nanf_bits(c2) ? p2 : c2;
  }
}

extern "C" void kernel_launch(void* const* d_in, const int* in_sizes, int n_in,
                              void* d_out, int out_size, void* d_ws, size_t ws_size,
                              hipStream_t stream) {
  const float* cat_seq = (const float*)d_in[0];
  const float* val_seq = (const float*)d_in[1];
  const float* Wih0 = (const float*)d_in[2];
  const float* Whh0 = (const float*)d_in[3];
  const float* b0 = (const float*)d_in[4];
  const float* Wih1 = (const float*)d_in[5];
  const float* Whh1 = (const float*)d_in[6];
  const float* b1 = (const float*)d_in[7];
  const float* Wc = (const float*)d_in[8];
  const float* bc = (const float*)d_in[9];
  const float* Wm = (const float*)d_in[10];
  const float* bm = (const float*)d_in[11];
  float* ws = (float*)d_ws;
  float* Wc0 = ws + OFF_WCAT0;
  float* Wc1 = ws + OFF_WCAT1;
  float* h0b[2] = {ws + OFF_H0, ws + OFF_H0 + SZ_HBUF};
  float* h1b[2] = {ws + OFF_H1, ws + OFF_H1 + SZ_HBUF};
  float* catb[2] = {ws + OFF_CAT, ws + OFF_CAT + SZ_CATB};
  float* valb[2] = {ws + OFF_VAL, ws + OFF_VAL + SZ_VALB};
  float* out = (float*)d_out;

  hipLaunchKernelGGL(pack_weights, dim3(2048), dim3(256), 0, stream,
                     Wih0, Whh0, Wih1, Whh1, Wc0, Wc1);
  hipLaunchKernelGGL(init_state, dim3(512), dim3(256), 0, stream,
                     cat_seq, val_seq, h0b[0], h1b[0], catb[0], valb[0]);
  int p = 0;
  for (int i = 0; i < 199; ++i) {
    int q = p ^ 1;
    hipLaunchKernelGGL((step_gemm<0>), dim3(32, 8), dim3(256), 0, stream,
                       valb[p], h0b[p], catb[p], Wc0, b0, h0b[q]);
    hipLaunchKernelGGL((step_gemm<1>), dim3(32, 8), dim3(256), 0, stream,
                       h0b[q], h1b[p], (const float*)nullptr, Wc1, b1, h1b[q]);
    hipLaunchKernelGGL(phase_c, dim3(32), dim3(256), 0, stream,
                       h1b[q], valb[p], cat_seq, val_seq, Wc, bc, Wm, bm,
                       out, catb[q], valb[q], i);
    p = q;
  }
}